// Round 11
// baseline (480.163 us; speedup 1.0000x reference)
//
#include <hip/hip_runtime.h>
#include <math.h>

#define N 1024
#define C 384
#define H 12
#define DP 128
#define HP 144
#define MT 64   // keys per tile
#define NSUP 8  // super-tiles (128 m each: pb phase + 2 QK/AV tiles)
#define SCALING 0.17677669529663687f
#define LN_EPS 1e-5f

// ---------------- K1: fused projections GEMM (r8, unchanged) ----------------
__global__ __launch_bounds__(256) void k_qkv(
    const float* __restrict__ single,
    const float* __restrict__ Wq, const float* __restrict__ bq,
    const float* __restrict__ Wk, const float* __restrict__ bk,
    const float* __restrict__ Wv, const float* __restrict__ bv,
    const float* __restrict__ Wpq, const float* __restrict__ bpq,
    const float* __restrict__ Wpk, const float* __restrict__ bpk,
    float* __restrict__ q, float* __restrict__ kcg, float* __restrict__ v,
    float* __restrict__ qp, float* __restrict__ kp)
{
  __shared__ __align__(16) float A_s[64 * 33];
  __shared__ __align__(16) float B_s[32 * 48];
  int t = threadIdx.x;
  int nt = blockIdx.x, mt = blockIdx.y;
  int m0 = mt * 64;
  const float* W; const float* bias; int ld, kind, cb;
  if (nt < 8)       { W = Wq;  bias = bq;  ld = C;  cb = nt * 48;        kind = 0; }
  else if (nt < 16) { W = Wk;  bias = bk;  ld = C;  cb = (nt - 8) * 48;  kind = 1; }
  else if (nt < 24) { W = Wv;  bias = bv;  ld = C;  cb = (nt - 16) * 48; kind = 2; }
  else if (nt < 27) { W = Wpq; bias = bpq; ld = HP; cb = (nt - 24) * 48; kind = 3; }
  else              { W = Wpk; bias = bpk; ld = HP; cb = (nt - 27) * 48; kind = 4; }
  int tr = t >> 4, tc = t & 15;
  float acc[4][3] = {};
  for (int k0 = 0; k0 < C; k0 += 32) {
    if (k0) __syncthreads();
    #pragma unroll
    for (int i = 0; i < 8; i++) {
      int fi = i * 256 + t; int row = fi >> 5, col = fi & 31;
      A_s[row * 33 + col] = single[(m0 + row) * C + k0 + col];
    }
    #pragma unroll
    for (int i = 0; i < 6; i++) {
      int fi = i * 256 + t; int row = fi / 48, col = fi % 48;
      B_s[row * 48 + col] = W[(k0 + row) * ld + cb + col];
    }
    __syncthreads();
    #pragma unroll
    for (int k = 0; k < 32; k++) {
      float a[4], b[3];
      #pragma unroll
      for (int r = 0; r < 4; r++) a[r] = A_s[(tr * 4 + r) * 33 + k];
      #pragma unroll
      for (int c = 0; c < 3; c++) b[c] = B_s[k * 48 + tc * 3 + c];
      #pragma unroll
      for (int r = 0; r < 4; r++)
        #pragma unroll
        for (int c = 0; c < 3; c++) acc[r][c] = fmaf(a[r], b[c], acc[r][c]);
    }
  }
  #pragma unroll
  for (int c = 0; c < 3; c++) {
    int col = cb + tc * 3 + c;
    float bb = bias[col];
    #pragma unroll
    for (int r = 0; r < 4; r++) {
      int row = m0 + tr * 4 + r;
      float val = acc[r][c] + bb;
      if (kind == 0)      q[row * C + col] = val;
      else if (kind == 1) kcg[((col >> 5) * N + row) * 48 + (col & 31)] = val;
      else if (kind == 2) v[row * C + col] = val;
      else if (kind == 3) qp[row * HP + col] = val;
      else                kp[row * HP + col] = val;
    }
  }
}

// ---------------- K1b: rotate points, sq/sk sums (r8, unchanged) ----------------
__global__ __launch_bounds__(256) void k_rot(
    const float* __restrict__ qp, const float* __restrict__ kp,
    const float* __restrict__ rot,
    float* __restrict__ qg, float* __restrict__ kcg,
    float* __restrict__ sq, float* __restrict__ sknh)
{
  __shared__ __align__(16) float qp_s[HP], kp_s[HP], rot_s[9], q2_s[HP], k2_s[HP];
  int n = blockIdx.x, t = threadIdx.x;
  if (t < HP) { qp_s[t] = qp[n * HP + t]; kp_s[t] = kp[n * HP + t]; }
  if (t < 9)  rot_s[t] = rot[n * 9 + t];
  __syncthreads();
  if (t < HP) {
    int h = t / 12, r12 = t % 12, y = r12 >> 2, p = r12 & 3;
    float qgv = rot_s[y*3] * qp_s[h*12 + p] + rot_s[y*3+1] * qp_s[h*12 + 4 + p]
              + rot_s[y*3+2] * qp_s[h*12 + 8 + p];
    float kgv = rot_s[y*3] * kp_s[h*12 + p] + rot_s[y*3+1] * kp_s[h*12 + 4 + p]
              + rot_s[y*3+2] * kp_s[h*12 + 8 + p];
    qg[n * HP + t] = qgv;
    kcg[(h * N + n) * 48 + 32 + r12] = kgv;
    q2_s[t] = qgv * qgv; k2_s[t] = kgv * kgv;
  }
  if (t < 48) kcg[((t >> 2) * N + n) * 48 + 44 + (t & 3)] = 0.f;  // zero pad
  __syncthreads();
  if (t < H) {
    float s1 = 0.f, s2 = 0.f;
    #pragma unroll
    for (int e = 0; e < 12; e++) { s1 += q2_s[t * 12 + e]; s2 += k2_s[t * 12 + e]; }
    sq[n * H + t] = s1; sknh[n * H + t] = s2;
  }
}

// ---------------- K1c: LDS-tiled transpose kcg/v -> kcT/vT ----------------
// Coalesced float4 on BOTH global sides; scatter absorbed by LDS.
// kcT[h][c4(12)][n][4], vT[h][c4(8)][n][4].
__global__ __launch_bounds__(256) void k_tr(
    const float* __restrict__ kcg, const float* __restrict__ v,
    float* __restrict__ kcT, float* __restrict__ vT)
{
  __shared__ __align__(16) float4 ks[64][13];  // pad 13
  __shared__ __align__(16) float4 vs[64][9];   // pad 9
  int bid = blockIdx.x;
  int h = bid >> 4, n0 = (bid & 15) * 64;
  int t = threadIdx.x;
  #pragma unroll
  for (int i = 0; i < 3; i++) {
    int f = i * 256 + t; int row = f / 12, c4 = f % 12;
    ks[row][c4] = *(const float4*)&kcg[((long)h * N + n0 + row) * 48 + c4 * 4];
  }
  #pragma unroll
  for (int i = 0; i < 2; i++) {
    int f = i * 256 + t; int row = f >> 3, c4 = f & 7;
    vs[row][c4] = *(const float4*)&v[(n0 + row) * C + h * 32 + c4 * 4];
  }
  __syncthreads();
  float4* kcT4 = (float4*)kcT;
  float4* vT4  = (float4*)vT;
  #pragma unroll
  for (int i = 0; i < 3; i++) {
    int f = i * 256 + t; int c4 = f >> 6, row = f & 63;
    kcT4[(long)(h * 12 + c4) * N + n0 + row] = ks[row][c4];
  }
  #pragma unroll
  for (int i = 0; i < 2; i++) {
    int f = i * 256 + t; int c4 = f >> 6, row = f & 63;
    vT4[(long)(h * 8 + c4) * N + n0 + row] = vs[row][c4];
  }
}

// ---------------- K2: FUSED pair-bias + attention ----------------
// One block per query row n. Per 128-m super-tile:
//   PB phase: k_pb's 4-lane-per-row dot (quad q_ handles rows M0+q_ and
//             M0+64+q_, Wp shared) -> pbx_lds[2][12][64] (raw logit bias).
//   QK/AV:    wave = 3 heads, lane = m. kc/v coalesced from kcT/vT,
//             max-free softmax (validated r7/r8), o_ in VGPRs, butterfly
//             transpose-reduce (validated r10). pb never hits HBM.
__global__ __launch_bounds__(256, 2) void k_fused(
    const float4* __restrict__ pair4, const float* __restrict__ Wp,
    const float* __restrict__ bp, const float* __restrict__ sq,
    const float* __restrict__ sknh, const float* __restrict__ q,
    const float* __restrict__ qg, const float* __restrict__ kcT,
    const float* __restrict__ vT, float* __restrict__ wt)
{
  __shared__ __align__(16) float wp_s[12 * 128];   // [h][d]
  __shared__ __align__(16) float qc_s[12][48];     // S-prescaled [q|qg|0] per head
  __shared__ __align__(16) float pbx[2][12][64];   // raw bias for 2 sub-tiles
  __shared__ float sq_s[12], bp_s[12];

  int t = threadIdx.x;
  int n = blockIdx.x;
  int w = t >> 6, lane = t & 63;
  int q_ = t >> 2, tc = t & 3;

  #pragma unroll
  for (int i = 0; i < 6; i++) {
    int fi = i * 256 + t; int h = fi >> 7, d = fi & 127;
    wp_s[h * 128 + d] = Wp[d * 12 + h];
  }
  if (t < 12) { sq_s[t] = sq[n * 12 + t]; bp_s[t] = bp[t]; }
  if (t < 144) {
    int h = t / 12, c4 = t % 12;
    float4 val;
    if (c4 < 8)       val = *(const float4*)&q[n * C + h * 32 + c4 * 4];
    else if (c4 < 11) val = *(const float4*)&qg[n * HP + h * 12 + (c4 - 8) * 4];
    else              val = make_float4(0.f, 0.f, 0.f, 0.f);
    val.x *= SCALING; val.y *= SCALING; val.z *= SCALING; val.w *= SCALING;
    *(float4*)&qc_s[h][c4 * 4] = val;
  }
  __syncthreads();

  const float4* wp4 = (const float4*)wp_s;
  const float4* kcT4 = (const float4*)kcT;
  const float4* vT4  = (const float4*)vT;
  int h0 = w * 3;
  float lsum[3] = {};
  float o_[3][32] = {};

  for (int s = 0; s < NSUP; s++) {
    int M0 = s * 128;
    // ---- PB phase: rows M0+q_ (A) and M0+64+q_ (B) ----
    const float4* rpA = pair4 + ((long)n * N + M0 + q_) * 32;
    const float4* rpB = rpA + 64 * 32;
    float accA[12] = {}, accB[12] = {};
    #pragma unroll
    for (int i = 0; i < 8; i++) {
      float4 a = rpA[i * 4 + tc];
      float4 b = rpB[i * 4 + tc];
      #pragma unroll
      for (int h = 0; h < 12; h++) {
        float4 ww = wp4[h * 32 + i * 4 + tc];
        accA[h] = fmaf(a.x, ww.x, accA[h]);
        accA[h] = fmaf(a.y, ww.y, accA[h]);
        accA[h] = fmaf(a.z, ww.z, accA[h]);
        accA[h] = fmaf(a.w, ww.w, accA[h]);
        accB[h] = fmaf(b.x, ww.x, accB[h]);
        accB[h] = fmaf(b.y, ww.y, accB[h]);
        accB[h] = fmaf(b.z, ww.z, accB[h]);
        accB[h] = fmaf(b.w, ww.w, accB[h]);
      }
    }
    #pragma unroll
    for (int h = 0; h < 12; h++) {
      accA[h] += __shfl_xor(accA[h], 1);
      accA[h] += __shfl_xor(accA[h], 2);
      accB[h] += __shfl_xor(accB[h], 1);
      accB[h] += __shfl_xor(accB[h], 2);
    }
    __syncthreads();   // previous super's QK reads of pbx are done
    if (tc == 0) {
      float skA[12], skB[12];
      #pragma unroll
      for (int i = 0; i < 3; i++) {
        *(float4*)&skA[i * 4] = *(const float4*)&sknh[(M0 + q_) * 12 + i * 4];
        *(float4*)&skB[i * 4] = *(const float4*)&sknh[(M0 + 64 + q_) * 12 + i * 4];
      }
      #pragma unroll
      for (int h = 0; h < 12; h++) {
        pbx[0][h][q_] = accA[h] + bp_s[h] - 0.5f * SCALING * (sq_s[h] + skA[h]);
        pbx[1][h][q_] = accB[h] + bp_s[h] - 0.5f * SCALING * (sq_s[h] + skB[h]);
      }
    }
    __syncthreads();   // pbx visible
    // ---- QK + max-free softmax + AV, 2 sub-tiles ----
    #pragma unroll
    for (int sub = 0; sub < 2; sub++) {
      int moff = M0 + sub * 64;
      float L[3];
      #pragma unroll
      for (int hh = 0; hh < 3; hh++) L[hh] = pbx[sub][h0 + hh][lane];
      #pragma unroll
      for (int c4 = 0; c4 < 11; c4++) {
        #pragma unroll
        for (int hh = 0; hh < 3; hh++) {
          float4 kv = kcT4[(long)((h0 + hh) * 12 + c4) * N + moff + lane];
          float4 qv = *(const float4*)&qc_s[h0 + hh][c4 * 4];
          L[hh] = fmaf(qv.x, kv.x, L[hh]);
          L[hh] = fmaf(qv.y, kv.y, L[hh]);
          L[hh] = fmaf(qv.z, kv.z, L[hh]);
          L[hh] = fmaf(qv.w, kv.w, L[hh]);
        }
      }
      float p[3];
      #pragma unroll
      for (int hh = 0; hh < 3; hh++) {
        p[hh] = __expf(L[hh]);
        lsum[hh] += p[hh];
      }
      #pragma unroll
      for (int c4 = 0; c4 < 8; c4++) {
        #pragma unroll
        for (int hh = 0; hh < 3; hh++) {
          float4 vv = vT4[(long)((h0 + hh) * 8 + c4) * N + moff + lane];
          o_[hh][c4*4+0] = fmaf(p[hh], vv.x, o_[hh][c4*4+0]);
          o_[hh][c4*4+1] = fmaf(p[hh], vv.y, o_[hh][c4*4+1]);
          o_[hh][c4*4+2] = fmaf(p[hh], vv.z, o_[hh][c4*4+2]);
          o_[hh][c4*4+3] = fmaf(p[hh], vv.w, o_[hh][c4*4+3]);
        }
      }
    }
  }

  // ---- epilogue: reduce lsum + butterfly transpose-reduce o_ (r10-proven) ----
  #pragma unroll
  for (int hh = 0; hh < 3; hh++) {
    #pragma unroll
    for (int off = 32; off; off >>= 1) lsum[hh] += __shfl_xor(lsum[hh], off);
  }
  #pragma unroll
  for (int hh = 0; hh < 3; hh++) {
    float c16[16], c8[8], c4a[4], c2[2], c1;
    int b = lane & 1;
    #pragma unroll
    for (int j = 0; j < 16; j++) {
      float keep = b ? o_[hh][2*j+1] : o_[hh][2*j];
      float send = b ? o_[hh][2*j]   : o_[hh][2*j+1];
      c16[j] = keep + __shfl_xor(send, 1);
    }
    b = lane & 2;
    #pragma unroll
    for (int j = 0; j < 8; j++) {
      float keep = b ? c16[2*j+1] : c16[2*j];
      float send = b ? c16[2*j]   : c16[2*j+1];
      c8[j] = keep + __shfl_xor(send, 2);
    }
    b = lane & 4;
    #pragma unroll
    for (int j = 0; j < 4; j++) {
      float keep = b ? c8[2*j+1] : c8[2*j];
      float send = b ? c8[2*j]   : c8[2*j+1];
      c4a[j] = keep + __shfl_xor(send, 4);
    }
    b = lane & 8;
    #pragma unroll
    for (int j = 0; j < 2; j++) {
      float keep = b ? c4a[2*j+1] : c4a[2*j];
      float send = b ? c4a[2*j]   : c4a[2*j+1];
      c2[j] = keep + __shfl_xor(send, 8);
    }
    b = lane & 16;
    {
      float keep = b ? c2[1] : c2[0];
      float send = b ? c2[0] : c2[1];
      c1 = keep + __shfl_xor(send, 16);
    }
    c1 += __shfl_xor(c1, 32);
    if (lane < 32) wt[n * C + (h0 + hh) * 32 + lane] = c1 / lsum[hh];
  }
}

// ---------------- K4: output GEMM + residual + LayerNorm (r8, unchanged) ----------------
__global__ __launch_bounds__(384) void k_out(
    const float* __restrict__ wt, const float* __restrict__ Wo,
    const float* __restrict__ bo, const float* __restrict__ single,
    const float* __restrict__ gamma, const float* __restrict__ beta,
    float* __restrict__ out)
{
  __shared__ __align__(16) float wt_s[4 * C];
  __shared__ __align__(16) float red[4][2][6];
  int t = threadIdx.x, n0 = blockIdx.x * 4;
  for (int idx = t; idx < 4 * C; idx += 384) wt_s[idx] = wt[n0 * C + idx];
  __syncthreads();
  float acc[4] = {};
  for (int ck = 0; ck < C; ck++) {
    float w = Wo[ck * C + t];
    #pragma unroll
    for (int i = 0; i < 4; i++) acc[i] = fmaf(wt_s[i * C + ck], w, acc[i]);
  }
  float x[4], bov = bo[t];
  #pragma unroll
  for (int i = 0; i < 4; i++) x[i] = single[(n0 + i) * C + t] + acc[i] + bov;
  int wid = t >> 6, lane = t & 63;
  #pragma unroll
  for (int i = 0; i < 4; i++) {
    float s = x[i], s2 = x[i] * x[i];
    #pragma unroll
    for (int off = 32; off; off >>= 1) { s += __shfl_xor(s, off); s2 += __shfl_xor(s2, off); }
    if (lane == 0) { red[i][0][wid] = s; red[i][1][wid] = s2; }
  }
  __syncthreads();
  float gv = gamma[t], bv = beta[t];
  #pragma unroll
  for (int i = 0; i < 4; i++) {
    float S = 0.f, S2 = 0.f;
    #pragma unroll
    for (int w = 0; w < 6; w++) { S += red[i][0][w]; S2 += red[i][1][w]; }
    float mu = S * (1.0f / C);
    float var = S2 * (1.0f / C) - mu * mu;
    out[(n0 + i) * C + t] = (x[i] - mu) * rsqrtf(var + LN_EPS) * gv + bv;
  }
}

extern "C" void kernel_launch(void* const* d_in, const int* in_sizes, int n_in,
                              void* d_out, int out_size, void* d_ws, size_t ws_size,
                              hipStream_t stream) {
  const float* single = (const float*)d_in[0];
  const float* pair   = (const float*)d_in[1];
  const float* rot    = (const float*)d_in[2];
  const float* Wq  = (const float*)d_in[4];  const float* bq  = (const float*)d_in[5];
  const float* Wk  = (const float*)d_in[6];  const float* bk  = (const float*)d_in[7];
  const float* Wv  = (const float*)d_in[8];  const float* bv  = (const float*)d_in[9];
  const float* Wp  = (const float*)d_in[10]; const float* bp  = (const float*)d_in[11];
  const float* Wpq = (const float*)d_in[12]; const float* bpq = (const float*)d_in[13];
  const float* Wpk = (const float*)d_in[14]; const float* bpk = (const float*)d_in[15];
  const float* Wo  = (const float*)d_in[16]; const float* bo  = (const float*)d_in[17];
  const float* gamma = (const float*)d_in[18]; const float* beta = (const float*)d_in[19];

  float* ws   = (float*)d_ws;
  float* q    = ws;                          // [N][C]
  float* v    = q + N * C;                   // [N][C]
  float* qp   = v + N * C;                   // [N][HP]
  float* kp   = qp + N * HP;                 // [N][HP]
  float* qg   = kp + N * HP;                 // [N][HP]
  float* kcg  = qg + N * HP;                 // [12][N][48]
  float* sq   = kcg + 12L * N * 48;          // [N][12]
  float* sknh = sq + N * H;                  // [N][12]
  float* wt   = sknh + N * H;                // [N][C]
  float* kcT  = wt + N * C;                  // [12][12][N][4]
  float* vT   = kcT + 12L * 12 * N * 4;      // [12][8][N][4]

  k_qkv<<<dim3(30, 16), 256, 0, stream>>>(single, Wq, bq, Wk, bk, Wv, bv,
                                          Wpq, bpq, Wpk, bpk, q, kcg, v, qp, kp);
  k_rot<<<N, 256, 0, stream>>>(qp, kp, rot, qg, kcg, sq, sknh);
  k_tr<<<192, 256, 0, stream>>>(kcg, v, kcT, vT);
  k_fused<<<N, 256, 0, stream>>>((const float4*)pair, Wp, bp, sq, sknh,
                                 q, qg, kcT, vT, wt);
  k_out<<<256, 384, 0, stream>>>(wt, Wo, bo, single, gamma, beta, (float*)d_out);
}